// Round 7
// baseline (790.682 us; speedup 1.0000x reference)
//
#include <hip/hip_runtime.h>

// Differentiable EXP-HYDRO: B=128, T=4096, F=20; MLP(15->256->64->6) + sequential scan.
// Checker: absolute threshold = 2% of max|q_ref| = 3.7e-13 -> full fp32 only
// (bf16/approx anywhere upstream of s1 dynamics blows e^{10*ds1} error growth).
// K1 mlp_kernel : params per (b,t) + step-invariant precompute -> 3 SoA float4 arrays
// K2 scan_kernel: 128 chains over 2 blocks x 64 lanes; SoA loads are 1KB/inst coalesced
// K3 qout_kernel: q = qsub+qsurf at (s1[t], params); LDS transpose to (B,T)

#define BB   128
#define TT   4096
#define NPOS (BB * TT)

#define L2E   1.4426950408889634f     // log2(e)
#define L10F  14.426950408889634f     // 10*log2(e)
#define FL2C  0.14426950408889634f    // (1/10)*log2(e)
#define CLIPF 100000.0f

__device__ __forceinline__ float fexp2(float x) { return __builtin_amdgcn_exp2f(x); }
__device__ __forceinline__ float frcp(float x)  { return __builtin_amdgcn_rcpf(x); }
// heaviside(x) = (tanh(5x)+1)/2 = sigmoid(10x)
__device__ __forceinline__ float sig10(float x) { return frcp(1.0f + fexp2(-L10F * x)); }
__device__ __forceinline__ float sigm(float x)  { return frcp(1.0f + fexp2(-L2E * x)); }
__device__ __forceinline__ float tanh_fast(float x) {
    float e = fexp2(2.0f * L2E * x);
    return 1.0f - 2.0f * frcp(e + 1.0f);
}

// ---------------------------------------------------------------- K1: MLP ----
// No LDS: weight accesses are wave-uniform on const __restrict__ pointers ->
// scalar (SMEM) loads; VALU pipe stays free for FMAs.
__global__ __launch_bounds__(256) void mlp_kernel(
    const float* __restrict__ inp, const float* __restrict__ w1,
    const float* __restrict__ b1,  const float* __restrict__ w2,
    const float* __restrict__ b2,  const float* __restrict__ w3,
    const float* __restrict__ b3,
    float4* __restrict__ par0, float4* __restrict__ par1, float4* __restrict__ par2)
{
    const int pos = blockIdx.x * 256 + threadIdx.x;   // pos = t*128 + b (b fastest)
    const int b   = pos & 127;
    const int t   = pos >> 7;

    const float4* xin = (const float4*)(inp + ((size_t)b * TT + t) * 20);
    float4 i0 = xin[0], i1 = xin[1], i2 = xin[2], i3 = xin[3], i4 = xin[4];
    const float pet = i0.x, tme = i0.y, prcp = i0.z;
    float x[15];
    x[0]=i1.y;  x[1]=i1.z;  x[2]=i1.w;
    x[3]=i2.x;  x[4]=i2.y;  x[5]=i2.z;  x[6]=i2.w;
    x[7]=i3.x;  x[8]=i3.y;  x[9]=i3.z;  x[10]=i3.w;
    x[11]=i4.x; x[12]=i4.y; x[13]=i4.z; x[14]=i4.w;

    float acc2[64];
    #pragma unroll
    for (int j = 0; j < 64; ++j) acc2[j] = b2[j];

    #pragma unroll 1
    for (int c = 0; c < 8; ++c) {             // 8 chunks of 32 hidden units
        float h[32];
        #pragma unroll
        for (int j = 0; j < 32; ++j) {
            const int col = c * 32 + j;
            float pre = b1[col];
            #pragma unroll
            for (int k = 0; k < 15; ++k) pre = fmaf(x[k], w1[k * 256 + col], pre);
            h[j] = tanh_fast(pre);
        }
        #pragma unroll
        for (int k2 = 0; k2 < 32; ++k2) {
            const float hv = h[k2];
            const int row = (c * 32 + k2) * 64;
            #pragma unroll
            for (int j = 0; j < 64; ++j)
                acc2[j] = fmaf(hv, w2[row + j], acc2[j]);
        }
    }

    float p[6];
    #pragma unroll
    for (int o = 0; o < 6; ++o) p[o] = b3[o];
    #pragma unroll
    for (int j = 0; j < 64; ++j) {
        const float h2 = tanh_fast(acc2[j]);
        #pragma unroll
        for (int o = 0; o < 6; ++o) p[o] = fmaf(h2, w3[j * 6 + o], p[o]);
    }
    const float tmin_p = sigm(p[0]), tmax_p = sigm(p[1]), ddf_p = sigm(p[2]);
    const float f_p    = sigm(p[3]), smax_p = sigm(p[4]), qmax_p = sigm(p[5]);

    // step-invariant precompute
    const float tmn   = -3.0f * tmin_p;
    const float g     = sig10(tmn - tme);
    const float psnow = g * prcp;
    const float prain = prcp - psnow;
    const float tmx3  = 3.0f * tmax_p;
    const float hm    = sig10(tme - tmx3);
    const float dd    = 5.0f * ddf_p * (tme - tmx3);
    const float smax  = fmaf(1400.0f, smax_p, 100.0f);
    const float qmax  = fmaf(40.0f, qmax_p, 10.0f);
    const float pr    = pet * frcp(smax);          // pet/smax
    const float pr2   = 1.0f - pr;
    const float C1c   = pet + qmax - smax;
    const float fl2   = FL2C * f_p;                // (f/10)*log2e
    const float flsmax  = fl2 * smax;
    const float l10smax = L10F * smax;

    par0[pos] = make_float4(psnow, prain, hm, dd);
    par1[pos] = make_float4(C1c, pr, pr2, qmax);
    par2[pos] = make_float4(fl2, flsmax, l10smax, smax);
}

// --------------------------------------------------------------- K2: scan ----
#define SC     4        // timesteps per chunk

#define LOADC(cc, N) { _Pragma("unroll")                                         \
    for (int s_ = 0; s_ < SC; ++s_) {                                            \
        const int p_ = ((cc) * SC + s_) * 128 + chain;                           \
        N##0[s_] = par0[p_]; N##1[s_] = par1[p_]; N##2[s_] = par2[p_];           \
    } }

#define COMPC(cc, N) { _Pragma("unroll")                                         \
    for (int s_ = 0; s_ < SC; ++s_) {                                            \
        const float psnow_ = N##0[s_].x, prain_ = N##0[s_].y;                    \
        const float hm_ = N##0[s_].z, dd_ = N##0[s_].w;                          \
        const float c1_ = N##1[s_].x, pr_ = N##1[s_].y;                          \
        const float pr2_ = N##1[s_].z, qmax_ = N##1[s_].w;                       \
        const float fl2_ = N##2[s_].x, flsmax_ = N##2[s_].y;                     \
        const float l10smax_ = N##2[s_].z;                                       \
        /* snow bucket */                                                        \
        const float h0_   = frcp(1.0f + fexp2(-L10F * s0));                      \
        const float melt_ = hm_ * h0_ * fminf(s0, dd_);                          \
        s0 = s0 + fminf(fmaxf(psnow_ - melt_, -CLIPF), CLIPF);                   \
        /* soil bucket: et+qsub+qsurf = h1*(ha*G + H) */                         \
        const float h1_ = frcp(1.0f + fexp2(-L10F * s1));                        \
        const float ha_ = frcp(1.0f + fexp2(fmaf(-L10F, s1, l10smax_)));         \
        const float ez_ = fexp2(fmaf(fl2_, s1, -flsmax_));                       \
        const float w_  = qmax_ * ez_;                                           \
        const float G_  = fmaf(s1, pr2_, c1_) - w_;                              \
        const float H_  = fmaf(s1, pr_, w_);                                     \
        const float ds1_ = fmaf(-h1_, fmaf(ha_, G_, H_), prain_ + melt_);        \
        s1 = s1 + fminf(fmaxf(ds1_, -CLIPF), CLIPF);                             \
        s1buf[((cc) * SC + s_) * 128 + chain] = s1;                              \
    } }

__global__ __launch_bounds__(64) void scan_kernel(
    const float4* __restrict__ par0, const float4* __restrict__ par1,
    const float4* __restrict__ par2, float* __restrict__ s1buf)
{
    const int chain = blockIdx.x * 64 + threadIdx.x;   // 2 blocks x 64 chains
    float s0 = 0.0f, s1 = 0.0f;

    float4 A0[SC], A1[SC], A2[SC];
    float4 B0[SC], B1[SC], B2[SC];
    float4 C0[SC], C1[SC], C2[SC];

    LOADC(0, A);
    LOADC(1, B);

    int c = 0;
    for (int it = 0; it < 341; ++it) {      // 341*3 = 1023 chunks in rotation
        LOADC(c + 2, C);
        COMPC(c, A);
        LOADC(c + 3, A);                    // c+3 <= 1023 always: valid
        COMPC(c + 1, B);
        if (it < 340) { LOADC(c + 4, B); }  // c+4 == 1024 on last iter: skip
        COMPC(c + 2, C);
        c += 3;
    }
    COMPC(1023, A);                          // final chunk (in A)
}

// --------------------------------------------------------------- K3: qout ----
__global__ __launch_bounds__(1024) void qout_kernel(
    const float4* __restrict__ par1, const float4* __restrict__ par2,
    const float* __restrict__ s1buf, float* __restrict__ out)
{
    __shared__ float tile[32][33];           // +1 pad: conflict-free transpose
    const int tid = threadIdx.x;
    const int b0  = (blockIdx.x & 3) * 32;
    const int t0  = (blockIdx.x >> 2) * 32;

    const int bl = tid & 31, tl = tid >> 5;
    const int pos = (t0 + tl) * 128 + (b0 + bl);
    const float s1 = s1buf[pos];
    const float4 v1 = par1[pos];             // C1, pr, pr2, qmax
    const float4 v2 = par2[pos];             // fl2, flsmax, l10smax, smax
    const float qmax = v1.w;
    const float fl2 = v2.x, flsmax = v2.y, l10smax = v2.z, smax = v2.w;

    const float a  = s1 - smax;
    const float h1 = frcp(1.0f + fexp2(-L10F * s1));
    const float ha = frcp(1.0f + fexp2(fmaf(-L10F, s1, l10smax)));
    const float ez = fexp2(fmaf(fl2, s1, -flsmax));
    const float w  = qmax * ez;
    const float q  = h1 * (fmaf(ha, (qmax - w) + a, w));   // qsub + qsurf

    tile[tl][bl] = q;
    __syncthreads();

    const int tl2 = tid & 31, bl2 = tid >> 5;
    out[(size_t)(b0 + bl2) * TT + (t0 + tl2)] = tile[tl2][bl2];
}

// ------------------------------------------------------------------ launch ---
extern "C" void kernel_launch(void* const* d_in, const int* in_sizes, int n_in,
                              void* d_out, int out_size, void* d_ws, size_t ws_size,
                              hipStream_t stream)
{
    (void)in_sizes; (void)n_in; (void)out_size; (void)ws_size;
    const float* inp = (const float*)d_in[0];
    const float* w1  = (const float*)d_in[1];
    const float* b1  = (const float*)d_in[2];
    const float* w2  = (const float*)d_in[3];
    const float* b2  = (const float*)d_in[4];
    const float* w3  = (const float*)d_in[5];
    const float* b3  = (const float*)d_in[6];
    float* out = (float*)d_out;

    float4* par0 = (float4*)d_ws;                    // NPOS float4 = 8 MB
    float4* par1 = par0 + NPOS;                      // 8 MB
    float4* par2 = par1 + NPOS;                      // 8 MB
    float*  s1buf = (float*)(par2 + NPOS);           // 2 MB  (total 26 MB)

    hipLaunchKernelGGL(mlp_kernel, dim3(NPOS / 256), dim3(256), 0, stream,
                       inp, w1, b1, w2, b2, w3, b3, par0, par1, par2);
    hipLaunchKernelGGL(scan_kernel, dim3(2), dim3(64), 0, stream,
                       par0, par1, par2, s1buf);
    hipLaunchKernelGGL(qout_kernel, dim3((BB / 32) * (TT / 32)), dim3(1024), 0, stream,
                       par1, par2, s1buf, out);
}